// Round 1
// baseline (489.306 us; speedup 1.0000x reference)
//
#include <hip/hip_runtime.h>
#include <cstdint>

// TTLinear: y = x @ W^T + bias, W (4096x4096) reconstructed from TT cores,
// then a bf16 MFMA GEMM.
//
// R4: GEMM rewritten from the 128x128 2-barrier structure (vmcnt(0) drain per
// K-step, MfmaUtil 55%) to a 256x256 / BK=32 / 8-wave kernel with a 4-deep
// LDS ring buffer and counted s_waitcnt vmcnt(8) (never 0 in steady state),
// raw s_barrier (no __syncthreads -> no compiler-forced drain), setprio(1)
// around MFMA clusters, and XCD-aware block swizzle. Staging of tile t+3 is
// issued while computing tile t; the target buffer was freed at end of tile
// t-1, so the schedule is race-free by construction.
//
// ws layout: [0,64MiB) xb bf16, [64MiB,96MiB) Wbt bf16 (N x K), then C01 fp32.

typedef __bf16 bf16x8 __attribute__((ext_vector_type(8)));
typedef float f32x4 __attribute__((ext_vector_type(4)));
typedef unsigned short u16;
typedef u16 u16x8 __attribute__((ext_vector_type(8)));

__device__ __forceinline__ u16 f2bf(float f) {
    unsigned u = __builtin_bit_cast(unsigned, f);
    u += 0x7fffu + ((u >> 16) & 1u);   // round-to-nearest-even
    return (u16)(u >> 16);
}

// ---- kernel 1: x fp32 -> bf16 (8 elems/thread, 16B stores) ----
__global__ void k_cvt(const float* __restrict__ x, u16* __restrict__ xb) {
    long i = (long)blockIdx.x * blockDim.x + threadIdx.x;   // one per 8 floats
    const float4* p = (const float4*)x;
    float4 a = p[2 * i], b = p[2 * i + 1];
    u16x8 o;
    o[0] = f2bf(a.x); o[1] = f2bf(a.y); o[2] = f2bf(a.z); o[3] = f2bf(a.w);
    o[4] = f2bf(b.x); o[5] = f2bf(b.y); o[6] = f2bf(b.z); o[7] = f2bf(b.w);
    ((u16x8*)xb)[i] = o;
}

// ---- kernel 2: C01[o0][o1][i0][i1][b2] = sum_b1 core0[0,o0,i0,b1]*core1[b1,o1,i1,b2]
__global__ void k_c01(const float* __restrict__ c0, const float* __restrict__ c1,
                      float* __restrict__ c01) {
    int idx = blockIdx.x * 256 + threadIdx.x;   // 524288 total
    int b2 = idx & 7, i1 = (idx >> 3) & 15, i0 = (idx >> 7) & 15;
    int o1 = (idx >> 11) & 15, o0 = idx >> 15;
    float s = 0.f;
#pragma unroll
    for (int b1 = 0; b1 < 8; ++b1)
        s += c0[(o0 * 16 + i0) * 8 + b1] * c1[((b1 * 16 + o1) * 16 + i1) * 8 + b2];
    c01[idx] = s;
}

// ---- kernel 3: Wbt[o][i] bf16 (B^T layout, N x K); thread computes 8 consecutive i
__global__ void k_w(const float* __restrict__ c01, const float* __restrict__ c2,
                    u16* __restrict__ wbt) {
    int idx = blockIdx.x * 256 + threadIdx.x;   // 2,097,152 total
    int i2h = idx & 1;
    int i1 = (idx >> 1) & 15;
    int i0 = (idx >> 5) & 15;
    int o = idx >> 9;                            // 0..4095
    int o2 = o & 15, o1 = (o >> 4) & 15, o0 = o >> 8;
    const float* c = &c01[(((o0 * 16 + o1) * 16 + i0) * 16 + i1) * 8];
    float acc[8] = {0, 0, 0, 0, 0, 0, 0, 0};
#pragma unroll
    for (int b2 = 0; b2 < 8; ++b2) {
        float cv = c[b2];
        const float* cc = &c2[(b2 * 16 + o2) * 16 + i2h * 8];
#pragma unroll
        for (int j = 0; j < 8; ++j) acc[j] += cv * cc[j];
    }
    u16x8 ov;
#pragma unroll
    for (int j = 0; j < 8; ++j) ov[j] = f2bf(acc[j]);
    ((u16x8*)wbt)[(long)o * 512 + (i0 * 32 + i1 * 2 + i2h)] = ov;
}

// ---- kernel 4: GEMM. C[m][n] = sum_k A[m,k]*B[n,k] + bias[n] ----
#define BM 256
#define BN 256
#define BK 32
#define NBUF 4
#define TA (BM * BK)                 // 8192 u16 per A tile (16 KiB)
#define TB (BN * BK)
#define LDS_BYTES (NBUF * (TA + TB) * 2)   // 131072

static_assert(LDS_BYTES == 131072, "lds size");

__device__ __forceinline__ void gload_lds16(const void* g, void* l) {
    __builtin_amdgcn_global_load_lds(
        (const __attribute__((address_space(1))) unsigned*)g,
        (__attribute__((address_space(3))) unsigned*)l, 16, 0, 0);
}

__launch_bounds__(512, 2)
__global__ void k_gemm(const u16* __restrict__ A, const u16* __restrict__ B,
                       const float* __restrict__ bias, float* __restrict__ C,
                       int M, int N, int K) {
    extern __shared__ __align__(16) u16 lds[];
    u16* lA = lds;                       // NBUF * TA
    u16* lB = lds + NBUF * TA;           // NBUF * TB

    // XCD-aware swizzle: 512 blocks, 8 XCDs, 64 blocks per XCD chunk.
    // Within a chunk bn varies fastest -> 32 co-resident CUs share A panels
    // (fits XCD L2); B panels stream from LLC.
    const int wg = blockIdx.x;
    const int swz = (wg & 7) * 64 + (wg >> 3);
    const int bn = swz & 15, bm = swz >> 4;       // 16 N-blocks x 32 M-blocks
    const int m0 = bm * BM, n0 = bn * BN;

    const int t = threadIdx.x;
    const int wave = t >> 6, lane = t & 63;
    const int wm = wave >> 2, wn = wave & 3;      // 2 (M) x 4 (N) waves
    const int lr = lane & 15, quad = lane >> 4;

    // Staging: tile = 256 rows x 32 cols bf16 = 1024 16B-chunks. Thread loads
    // chunks ci = j*512+t (j=0,1). LDS is linear in ci; the GLOBAL chunk is
    // pre-swizzled: row r = ci>>2, slot = ci&3, global chunk = slot^((r>>1)&3).
    // (4 chunks/row; XOR with (r>>1)&3 spreads a 16-row column-read over 8
    // banks -> 2-way aliasing = free.)
    const u16* pa[2]; const u16* pb[2]; int lof[2];
#pragma unroll
    for (int j = 0; j < 2; ++j) {
        int ci = j * 512 + t;
        int r = ci >> 2;
        int c = (ci & 3) ^ ((r >> 1) & 3);
        pa[j] = &A[(long)(m0 + r) * K + c * 8];
        pb[j] = &B[(long)(n0 + r) * K + c * 8];
        lof[j] = ci * 8;                 // u16 units
    }

    // Fragment read offsets (u16 units), same swizzle on the read side.
    int offA[8], offB[4];
#pragma unroll
    for (int mi = 0; mi < 8; ++mi) {
        int r = wm * 128 + mi * 16 + lr;
        offA[mi] = r * BK + ((quad ^ ((r >> 1) & 3)) << 3);
    }
#pragma unroll
    for (int ni = 0; ni < 4; ++ni) {
        int r = wn * 64 + ni * 16 + lr;
        offB[ni] = r * BK + ((quad ^ ((r >> 1) & 3)) << 3);
    }

    f32x4 acc[8][4];
#pragma unroll
    for (int mi = 0; mi < 8; ++mi)
#pragma unroll
        for (int ni = 0; ni < 4; ++ni) acc[mi][ni] = 0.f;

    const int NT = K / BK;   // 128

    // Prologue: stage tiles 0,1,2 (12 loads); vmcnt(8) -> tile0 landed.
#pragma unroll
    for (int tt = 0; tt < 3; ++tt) {
#pragma unroll
        for (int j = 0; j < 2; ++j)
            gload_lds16(pa[j] + (long)tt * BK, lA + tt * TA + lof[j]);
#pragma unroll
        for (int j = 0; j < 2; ++j)
            gload_lds16(pb[j] + (long)tt * BK, lB + tt * TB + lof[j]);
    }
    asm volatile("s_waitcnt vmcnt(8)" ::: "memory");
    __builtin_amdgcn_s_barrier();

    // Main loop. Invariant entering tile t: tiles t+1,t+2 in flight (8 loads
    // outstanding), tile t landed. During tile t we issue tile t+3 (+4), and
    // the end-of-tile vmcnt(8) retires tile t+1. Never drains to 0 until the
    // tail. Buffer (t+3)&3 was freed at end of tile t-1 -> race-free.
#pragma unroll 1
    for (int tb = 0; tb < NT; tb += 4) {
#pragma unroll
        for (int u = 0; u < 4; ++u) {
            const int tt = tb + u;
            const u16* aT = lA + u * TA;           // read buffer (tt & 3 == u)
            const u16* bT = lB + u * TB;
            const int sb = (u + 3) & 3;            // stage buffer
            const bool pre = (tt + 3 < NT);

            // ---- phase 0: stage A(t+3) | read B(all)+A(mi 0-3) | 16 MFMA ----
            if (pre) {
#pragma unroll
                for (int j = 0; j < 2; ++j)
                    gload_lds16(pa[j] + (long)(tt + 3) * BK, lA + sb * TA + lof[j]);
            }
            bf16x8 bf[4], af[4];
#pragma unroll
            for (int ni = 0; ni < 4; ++ni) bf[ni] = *(const bf16x8*)&bT[offB[ni]];
#pragma unroll
            for (int mi = 0; mi < 4; ++mi) af[mi] = *(const bf16x8*)&aT[offA[mi]];
            __builtin_amdgcn_s_barrier();
            __builtin_amdgcn_s_setprio(1);
#pragma unroll
            for (int mi = 0; mi < 4; ++mi)
#pragma unroll
                for (int ni = 0; ni < 4; ++ni)
                    acc[mi][ni] = __builtin_amdgcn_mfma_f32_16x16x32_bf16(
                        af[mi], bf[ni], acc[mi][ni], 0, 0, 0);
            __builtin_amdgcn_s_setprio(0);
            __builtin_amdgcn_s_barrier();

            // ---- phase 1: stage B(t+3) | read A(mi 4-7) | 16 MFMA ----
            if (pre) {
#pragma unroll
                for (int j = 0; j < 2; ++j)
                    gload_lds16(pb[j] + (long)(tt + 3) * BK, lB + sb * TB + lof[j]);
            }
#pragma unroll
            for (int mi = 0; mi < 4; ++mi) af[mi] = *(const bf16x8*)&aT[offA[4 + mi]];
            __builtin_amdgcn_s_barrier();
            __builtin_amdgcn_s_setprio(1);
#pragma unroll
            for (int mi = 0; mi < 4; ++mi)
#pragma unroll
                for (int ni = 0; ni < 4; ++ni)
                    acc[4 + mi][ni] = __builtin_amdgcn_mfma_f32_16x16x32_bf16(
                        af[mi], bf[ni], acc[4 + mi][ni], 0, 0, 0);
            __builtin_amdgcn_s_setprio(0);

            // end-of-tile: counted wait (tile t+1 landed), then barrier.
            if (pre)                 asm volatile("s_waitcnt vmcnt(8)" ::: "memory");
            else if (tt + 2 < NT)    asm volatile("s_waitcnt vmcnt(4)" ::: "memory");
            else if (tt + 1 < NT)    asm volatile("s_waitcnt vmcnt(0)" ::: "memory");
            __builtin_amdgcn_s_barrier();
        }
    }

    // Epilogue: D row = quad*4 + r (m), col = lr (n); add bias, store fp32.
#pragma unroll
    for (int ni = 0; ni < 4; ++ni) {
        int gn = n0 + wn * 64 + ni * 16 + lr;
        float bv = bias[gn];
#pragma unroll
        for (int mi = 0; mi < 8; ++mi) {
            int gm = m0 + wm * 128 + mi * 16 + quad * 4;
#pragma unroll
            for (int r = 0; r < 4; ++r)
                C[(long)(gm + r) * N + gn] = acc[mi][ni][r] + bv;
        }
    }
}

extern "C" void kernel_launch(void* const* d_in, const int* in_sizes, int n_in,
                              void* d_out, int out_size, void* d_ws, size_t ws_size,
                              hipStream_t stream) {
    const float* x = (const float*)d_in[0];
    const float* c0 = (const float*)d_in[1];
    const float* c1 = (const float*)d_in[2];
    const float* c2 = (const float*)d_in[3];
    const float* bias = (const float*)d_in[4];
    float* out = (float*)d_out;

    const int Mb = 8192, Nf = 4096, Kf = 4096;
    char* ws = (char*)d_ws;
    u16* xb = (u16*)ws;                                       // 67,108,864 B
    u16* wbt = (u16*)(ws + 67108864);                         // 33,554,432 B
    float* c01 = (float*)(ws + 67108864 + 33554432);          //  2,097,152 B

    // 128 KiB dynamic LDS (> 64 KiB static limit). Not a stream op; safe
    // under graph capture. Idempotent.
    hipFuncSetAttribute(reinterpret_cast<const void*>(k_gemm),
                        hipFuncAttributeMaxDynamicSharedMemorySize, LDS_BYTES);

    k_cvt<<<dim3((Mb * Kf / 8) / 256), 256, 0, stream>>>(x, xb);
    k_c01<<<dim3(2048), 256, 0, stream>>>(c0, c1, c01);
    k_w<<<dim3(8192), 256, 0, stream>>>(c01, c2, wbt);
    k_gemm<<<dim3((Mb / BM) * (Nf / BN)), dim3(512), LDS_BYTES, stream>>>(
        xb, wbt, bias, out, Mb, Nf, Kf);
}